// Round 1
// baseline (40.330 us; speedup 1.0000x reference)
//
#include <hip/hip_runtime.h>

#define PS   9
#define EPSF 1e-4f
#define H    256
#define W    256
#define HO   248          // valid output dim: 256 - 9 + 1
#define TILE 16
#define REG  24           // TILE + PS - 1

// score[b] = sum_{i,j,k} n1*n2 / (81*248*248)
__global__ __launch_bounds__(256) void ncc_kernel(
    const float* __restrict__ x1, const float* __restrict__ x2,
    float* __restrict__ out)
{
    __shared__ float A[REG][REG + 1];
    __shared__ float B[REG][REG + 1];

    const int b  = blockIdx.z;
    const int j0 = blockIdx.x * TILE;
    const int i0 = blockIdx.y * TILE;

    const float* p1 = x1 + (size_t)b * (H * W);
    const float* p2 = x2 + (size_t)b * (H * W);

    const int tx  = threadIdx.x;
    const int ty  = threadIdx.y;
    const int tid = ty * TILE + tx;

    // Stage 24x24 region of both images into LDS (576 elems, 256 threads -> 3 iters)
    for (int idx = tid; idx < REG * REG; idx += 256) {
        const int r  = idx / REG;
        const int c  = idx - r * REG;
        const int gi = i0 + r;
        const int gj = j0 + c;
        float a = 0.0f, bb = 0.0f;
        if (gi < H && gj < W) {
            a  = p1[gi * W + gj];
            bb = p2[gi * W + gj];
        }
        A[r][c] = a;
        B[r][c] = bb;
    }
    __syncthreads();

    const int i = i0 + ty;
    const int j = j0 + tx;

    float contrib = 0.0f;
    if (i < HO && j < HO) {
        float s1 = 0.0f, s2 = 0.0f, s11 = 0.0f, s22 = 0.0f, s12 = 0.0f;
        #pragma unroll
        for (int ki = 0; ki < PS; ++ki) {
            #pragma unroll
            for (int kj = 0; kj < PS; ++kj) {
                const float a = A[ty + ki][tx + kj];
                const float c = B[ty + ki][tx + kj];
                s1  += a;
                s2  += c;
                s11  = fmaf(a, a, s11);
                s22  = fmaf(c, c, s22);
                s12  = fmaf(a, c, s12);
            }
        }
        const float inv_n = 1.0f / 81.0f;
        const float mu1 = s1 * inv_n;
        const float mu2 = s2 * inv_n;
        const float v1  = fmaf(-mu1, mu1, s11 * inv_n) + EPSF;
        const float v2  = fmaf(-mu2, mu2, s22 * inv_n) + EPSF;
        const float cross = fmaf(-s1 * inv_n, s2, s12);
        contrib = cross * rsqrtf(v1 * v2);
    }

    // Reduce 256 threads -> 1 value; scale; one atomic per block.
    // Wave-level shuffle reduce (wave = 64 lanes).
    #pragma unroll
    for (int off = 32; off >= 1; off >>= 1)
        contrib += __shfl_down(contrib, off, 64);

    __shared__ float warp_part[4];
    const int lane = tid & 63;
    const int wid  = tid >> 6;
    if (lane == 0) warp_part[wid] = contrib;
    __syncthreads();

    if (tid == 0) {
        float total = warp_part[0] + warp_part[1] + warp_part[2] + warp_part[3];
        const float scale = 1.0f / (81.0f * (float)HO * (float)HO);
        atomicAdd(&out[b], total * scale);
    }
}

extern "C" void kernel_launch(void* const* d_in, const int* in_sizes, int n_in,
                              void* d_out, int out_size, void* d_ws, size_t ws_size,
                              hipStream_t stream) {
    const float* x1 = (const float*)d_in[0];
    const float* x2 = (const float*)d_in[1];
    float* out = (float*)d_out;

    // Harness poisons d_out once and does NOT re-poison between replays:
    // zero it ourselves every call (graph-capture-safe async memset).
    hipMemsetAsync(out, 0, (size_t)out_size * sizeof(float), stream);

    dim3 block(TILE, TILE);
    dim3 grid((HO + TILE - 1) / TILE, (HO + TILE - 1) / TILE, 8);  // 16 x 16 x 8
    ncc_kernel<<<grid, block, 0, stream>>>(x1, x2, out);
}

// Round 2
// 18.668 us; speedup vs baseline: 2.1604x; 2.1604x over previous
//
#include <hip/hip_runtime.h>

#define PS   9
#define EPSF 1e-4f
#define H    256
#define W    256
#define HO   248          // valid output dim: 256 - 9 + 1
#define TILE 16
#define REG  24           // TILE + PS - 1
#define NBLK 256          // (248/16 rounded up)^2 = 16*16 blocks per batch

// Stage 1: per-block partial sums of the NCC contributions -> ws[b*NBLK + blk]
__global__ __launch_bounds__(256) void ncc_kernel(
    const float* __restrict__ x1, const float* __restrict__ x2,
    float* __restrict__ ws)
{
    __shared__ float A[REG][REG + 1];
    __shared__ float B[REG][REG + 1];

    const int b  = blockIdx.z;
    const int j0 = blockIdx.x * TILE;
    const int i0 = blockIdx.y * TILE;

    const float* p1 = x1 + (size_t)b * (H * W);
    const float* p2 = x2 + (size_t)b * (H * W);

    const int tx  = threadIdx.x;
    const int ty  = threadIdx.y;
    const int tid = ty * TILE + tx;

    // Stage 24x24 region of both images into LDS (576 elems, 256 threads -> 3 iters)
    for (int idx = tid; idx < REG * REG; idx += 256) {
        const int r  = idx / REG;
        const int c  = idx - r * REG;
        const int gi = i0 + r;
        const int gj = j0 + c;
        float a = 0.0f, bb = 0.0f;
        if (gi < H && gj < W) {
            a  = p1[gi * W + gj];
            bb = p2[gi * W + gj];
        }
        A[r][c] = a;
        B[r][c] = bb;
    }
    __syncthreads();

    const int i = i0 + ty;
    const int j = j0 + tx;

    float contrib = 0.0f;
    if (i < HO && j < HO) {
        float s1 = 0.0f, s2 = 0.0f, s11 = 0.0f, s22 = 0.0f, s12 = 0.0f;
        #pragma unroll
        for (int ki = 0; ki < PS; ++ki) {
            #pragma unroll
            for (int kj = 0; kj < PS; ++kj) {
                const float a = A[ty + ki][tx + kj];
                const float c = B[ty + ki][tx + kj];
                s1  += a;
                s2  += c;
                s11  = fmaf(a, a, s11);
                s22  = fmaf(c, c, s22);
                s12  = fmaf(a, c, s12);
            }
        }
        const float inv_n = 1.0f / 81.0f;
        const float mu1 = s1 * inv_n;
        const float mu2 = s2 * inv_n;
        const float v1  = fmaf(-mu1, mu1, s11 * inv_n) + EPSF;
        const float v2  = fmaf(-mu2, mu2, s22 * inv_n) + EPSF;
        const float cross = fmaf(-s1 * inv_n, s2, s12);
        contrib = cross * rsqrtf(v1 * v2);
    }

    // Reduce 256 threads -> 1 partial; one global store per block (no atomics).
    #pragma unroll
    for (int off = 32; off >= 1; off >>= 1)
        contrib += __shfl_down(contrib, off, 64);

    __shared__ float warp_part[4];
    const int lane = tid & 63;
    const int wid  = tid >> 6;
    if (lane == 0) warp_part[wid] = contrib;
    __syncthreads();

    if (tid == 0) {
        const int blk = blockIdx.y * gridDim.x + blockIdx.x;
        ws[b * NBLK + blk] = warp_part[0] + warp_part[1] + warp_part[2] + warp_part[3];
    }
}

// Stage 2: sum NBLK partials per batch, scale, write out[b]. Overwrites out
// fully every call (no memset needed).
__global__ __launch_bounds__(256) void ncc_reduce_kernel(
    const float* __restrict__ ws, float* __restrict__ out)
{
    const int b   = blockIdx.x;
    const int tid = threadIdx.x;

    float v = ws[b * NBLK + tid];

    #pragma unroll
    for (int off = 32; off >= 1; off >>= 1)
        v += __shfl_down(v, off, 64);

    __shared__ float warp_part[4];
    const int lane = tid & 63;
    const int wid  = tid >> 6;
    if (lane == 0) warp_part[wid] = v;
    __syncthreads();

    if (tid == 0) {
        const float scale = 1.0f / (81.0f * (float)HO * (float)HO);
        out[b] = (warp_part[0] + warp_part[1] + warp_part[2] + warp_part[3]) * scale;
    }
}

extern "C" void kernel_launch(void* const* d_in, const int* in_sizes, int n_in,
                              void* d_out, int out_size, void* d_ws, size_t ws_size,
                              hipStream_t stream) {
    const float* x1 = (const float*)d_in[0];
    const float* x2 = (const float*)d_in[1];
    float* out = (float*)d_out;
    float* ws  = (float*)d_ws;   // 8 * 256 floats = 8 KB used

    dim3 block(TILE, TILE);
    dim3 grid((HO + TILE - 1) / TILE, (HO + TILE - 1) / TILE, 8);  // 16 x 16 x 8
    ncc_kernel<<<grid, block, 0, stream>>>(x1, x2, ws);
    ncc_reduce_kernel<<<dim3(8), dim3(256), 0, stream>>>(ws, out);
}

// Round 3
// 11.593 us; speedup vs baseline: 3.4788x; 1.6103x over previous
//
#include <hip/hip_runtime.h>

#define PS   9
#define EPSF 1e-4f
#define H    256
#define W    256
#define HO   248           // valid output dim: 256 - 9 + 1
#define OW   24            // output columns per block
#define OH   32            // output rows per block
#define PC   32            // pixel columns per block = OW + 8
#define CSTR 33            // padded LDS row stride (break bank-32 pattern)
#define GX   11            // ceil(248/24)
#define GY   8             // ceil(248/32)
#define NBLK (GX*GY)       // 88 partials per batch

// Separable NCC: per block, Phase 1 computes vertical 9-window column sums of
// the 5 quantities (a, b, a^2, b^2, ab) into LDS; Phase 2 slides a horizontal
// 9-window over those column sums, finalizes the correlation, reduces.
__global__ __launch_bounds__(256) void ncc_kernel(
    const float* __restrict__ x1, const float* __restrict__ x2,
    float* __restrict__ ws)
{
    __shared__ float C[5][OH][CSTR];   // 5*32*33*4 = 21120 B
    __shared__ float warp_part[4];

    const int b  = blockIdx.z;
    const int j0 = blockIdx.x * OW;
    const int i0 = blockIdx.y * OH;

    const float* p1 = x1 + (size_t)b * (H * W);
    const float* p2 = x2 + (size_t)b * (H * W);

    const int tid = threadIdx.x;

    // ---------------- Phase 1: vertical column sums ----------------
    // thread -> (pixel column c, row-group g); g covers 4 output rows.
    {
        const int c = tid & 31;        // 0..31
        const int g = tid >> 5;        // 0..7
        const int j = j0 + c;
        const bool jok = (j < W);
        const int ibase = i0 + g * 4;

        float av[12], bv[12];
        #pragma unroll
        for (int r = 0; r < 12; ++r) {
            const int i = ibase + r;
            const bool ok = jok && (i < H);
            av[r] = ok ? p1[i * W + j] : 0.0f;
            bv[r] = ok ? p2[i * W + j] : 0.0f;
        }

        float s1 = 0.0f, s2 = 0.0f, s11 = 0.0f, s22 = 0.0f, s12 = 0.0f;
        #pragma unroll
        for (int r = 0; r < 9; ++r) {
            s1 += av[r];
            s2 += bv[r];
            s11 = fmaf(av[r], av[r], s11);
            s22 = fmaf(bv[r], bv[r], s22);
            s12 = fmaf(av[r], bv[r], s12);
        }
        const int t0 = g * 4;
        C[0][t0][c] = s1;  C[1][t0][c] = s2;
        C[2][t0][c] = s11; C[3][t0][c] = s22; C[4][t0][c] = s12;

        #pragma unroll
        for (int tt = 1; tt < 4; ++tt) {
            const float an = av[tt + 8], bn = bv[tt + 8];
            const float ao = av[tt - 1], bo = bv[tt - 1];
            s1 += an - ao;
            s2 += bn - bo;
            s11 = fmaf(an, an, s11); s11 = fmaf(-ao, ao, s11);
            s22 = fmaf(bn, bn, s22); s22 = fmaf(-bo, bo, s22);
            s12 = fmaf(an, bn, s12); s12 = fmaf(-ao, bo, s12);
            const int t = t0 + tt;
            C[0][t][c] = s1;  C[1][t][c] = s2;
            C[2][t][c] = s11; C[3][t][c] = s22; C[4][t][c] = s12;
        }
    }
    __syncthreads();

    // ---------------- Phase 2: horizontal sliding window ----------------
    // thread -> (output row t, column group jg of 3 consecutive outputs)
    float contrib = 0.0f;
    {
        const int jg = tid & 7;        // 0..7  -> columns jg*3 .. jg*3+2
        const int t  = tid >> 3;       // 0..31
        const int t_out = i0 + t;
        const int jc0 = jg * 3;

        float Wq[3][5];
        #pragma unroll
        for (int q = 0; q < 5; ++q) {
            float cv[11];
            #pragma unroll
            for (int k = 0; k < 11; ++k)
                cv[k] = C[q][t][jc0 + k];
            float w = cv[0];
            #pragma unroll
            for (int k = 1; k < 9; ++k) w += cv[k];
            Wq[0][q] = w;
            Wq[1][q] = Wq[0][q] - cv[0] + cv[9];
            Wq[2][q] = Wq[1][q] - cv[1] + cv[10];
        }

        const float inv_n = 1.0f / 81.0f;
        #pragma unroll
        for (int m = 0; m < 3; ++m) {
            const int j_out = j0 + jc0 + m;
            if (t_out < HO && j_out < HO) {
                const float s1  = Wq[m][0], s2  = Wq[m][1];
                const float s11 = Wq[m][2], s22 = Wq[m][3], s12 = Wq[m][4];
                const float mu1 = s1 * inv_n;
                const float mu2 = s2 * inv_n;
                const float v1  = fmaf(-mu1, mu1, s11 * inv_n) + EPSF;
                const float v2  = fmaf(-mu2, mu2, s22 * inv_n) + EPSF;
                const float cross = fmaf(-mu1, s2, s12);
                contrib += cross * rsqrtf(v1 * v2);
            }
        }
    }

    // ---------------- block reduce -> one partial per block ----------------
    #pragma unroll
    for (int off = 32; off >= 1; off >>= 1)
        contrib += __shfl_down(contrib, off, 64);

    const int lane = tid & 63;
    const int wid  = tid >> 6;
    if (lane == 0) warp_part[wid] = contrib;
    __syncthreads();

    if (tid == 0) {
        const int blk = blockIdx.y * GX + blockIdx.x;
        ws[b * NBLK + blk] = warp_part[0] + warp_part[1] + warp_part[2] + warp_part[3];
    }
}

// Stage 2: sum NBLK partials per batch, scale, write out[b]. Overwrites out
// fully every call (no memset needed).
__global__ __launch_bounds__(128) void ncc_reduce_kernel(
    const float* __restrict__ ws, float* __restrict__ out)
{
    const int b   = blockIdx.x;
    const int tid = threadIdx.x;

    float v = (tid < NBLK) ? ws[b * NBLK + tid] : 0.0f;

    #pragma unroll
    for (int off = 32; off >= 1; off >>= 1)
        v += __shfl_down(v, off, 64);

    __shared__ float wp[2];
    const int lane = tid & 63;
    const int wv   = tid >> 6;
    if (lane == 0) wp[wv] = v;
    __syncthreads();

    if (tid == 0) {
        const float scale = 1.0f / (81.0f * (float)HO * (float)HO);
        out[b] = (wp[0] + wp[1]) * scale;
    }
}

extern "C" void kernel_launch(void* const* d_in, const int* in_sizes, int n_in,
                              void* d_out, int out_size, void* d_ws, size_t ws_size,
                              hipStream_t stream) {
    const float* x1 = (const float*)d_in[0];
    const float* x2 = (const float*)d_in[1];
    float* out = (float*)d_out;
    float* ws  = (float*)d_ws;   // 8 * 88 floats used

    dim3 block(256);
    dim3 grid(GX, GY, 8);        // 11 x 8 x 8 = 704 blocks
    ncc_kernel<<<grid, block, 0, stream>>>(x1, x2, ws);
    ncc_reduce_kernel<<<dim3(8), dim3(128), 0, stream>>>(ws, out);
}